// Round 1
// baseline (11320.160 us; speedup 1.0000x reference)
//
#include <hip/hip_runtime.h>

#define Dd 256
#define Nn 128
#define Hh 32
#define HSk 20
#define Tt 256
#define NWG 128
#define NT 256
#define ETAf 1e-3f

// ---------------- grid barrier (hand-rolled, device-scope) ----------------
__device__ __forceinline__ unsigned ld_ag(const unsigned* p) {
  return __hip_atomic_load(p, __ATOMIC_RELAXED, __HIP_MEMORY_SCOPE_AGENT);
}
__device__ __forceinline__ void st_ag(unsigned* p, unsigned v) {
  __hip_atomic_store(p, v, __ATOMIC_RELAXED, __HIP_MEMORY_SCOPE_AGENT);
}

__device__ __forceinline__ void grid_sync(unsigned* flags, unsigned* gen, unsigned b) {
  __threadfence();   // release: flush so our global writes reach device-coherent point
  __syncthreads();
  if (blockIdx.x == 0) {
    const int t = threadIdx.x;
    if (t > 0 && t < NWG) {
      while (ld_ag(&flags[t * 16]) < b) __builtin_amdgcn_s_sleep(1);
    }
    __syncthreads();
    if (t == 0) st_ag(gen, b);
  } else if (threadIdx.x == 0) {
    st_ag(&flags[blockIdx.x * 16], b);
    while (ld_ag(gen) < b) __builtin_amdgcn_s_sleep(1);
  }
  __syncthreads();
  __threadfence();   // acquire: invalidate stale L1/L2 before reading others' writes
}

__global__ void init_bar_kernel(unsigned* bar, int n) {
  for (int i = threadIdx.x; i < n; i += blockDim.x) bar[i] = 0u;
}

// ---------------- main persistent kernel ----------------
__global__ __launch_bounds__(NT, 1)
void osf_main(const float* __restrict__ Am, const float* __restrict__ Bm,
              const float* __restrict__ Qmat, const float* __restrict__ Rm,
              const float* __restrict__ Km, const float* __restrict__ phi,
              const float* __restrict__ sigma, const float* __restrict__ phis,
              const float* __restrict__ M0, const float* __restrict__ Ms,
              const float* __restrict__ x0, const float* __restrict__ W0,
              float* __restrict__ out, unsigned* __restrict__ bar,
              float* __restrict__ fws) {
  const int g = blockIdx.x;
  const int tid = threadIdx.x;

  unsigned* flags = bar;
  unsigned* gen = bar + NWG * 16;

  float* cnp  = fws;                    // [32][128]  sig4[h]*<M[h,n,:],v[:,h]>
  float* vbuf = cnp + Hh * Nn;          // [32][256]  v_t stored [h][d]
  float* phT  = vbuf + Hh * Dd;         // [20][128]  P_hist transposed [k][n]
  float* kx   = phT + HSk * Nn;         // [128]      K @ x_t
  float* xs   = kx + Nn;                // [256][256] x_t history (row t valid t>=1)
  float* u2   = xs + Tt * Dd;           // [256][128] u_t history

  __shared__ float s_u[Nn], s_part[2][Nn], s_urow[Tt], s_w[2][Tt];
  __shared__ float s_x[Dd], s_S[2][Nn], s_A[2][Dd], s_B[2][Nn], s_K[Dd];
  __shared__ float s_g[32], s_xh[2], s_red[NT], s_red4[NT], s_w0[2];

  const int h = g >> 2;          // owned filter index (M slice)
  const int n0 = (g & 3) * 32;   // owned n-range base (M slice)
  const int jj = tid >> 3;       // 0..31: n within slice
  const int dsub = tid & 7;      // 0..7: 32-wide d chunk
  const float sig4h = sqrtf(sqrtf(sigma[h]));

  // ---- init: per-WG constant rows into LDS ----
  for (int i = tid; i < Dd; i += NT) {
    s_A[0][i] = Am[(2 * g) * Dd + i];
    s_A[1][i] = Am[(2 * g + 1) * Dd + i];
    s_K[i] = Km[g * Dd + i];
  }
  for (int i = tid; i < Nn; i += NT) {
    float a0 = 0.f, a1 = 0.f;
    for (int k = 0; k < HSk; ++k) {             // S[d,:] = sum_k phis[0,k]*M_stu[k,d,:]
      a0 += phis[k] * Ms[(k * Dd + 2 * g) * Nn + i];
      a1 += phis[k] * Ms[(k * Dd + 2 * g + 1) * Nn + i];
    }
    s_S[0][i] = a0;
    s_S[1][i] = a1;
    s_B[0][i] = Bm[(2 * g) * Nn + i];
    s_B[1][i] = Bm[(2 * g + 1) * Nn + i];
  }
  if (tid < 2) s_w0[tid] = W0[(2 * g + tid) * 512];   // W0[:,0] only nonzero col

  // M slice resident in registers: M[h][n0+jj][dsub*32 .. +32]
  float4 Mreg[8], vp[8];
  {
    const float* mp = M0 + ((size_t)(h * Nn + n0 + jj) * Dd + dsub * 32);
#pragma unroll
    for (int e = 0; e < 8; ++e) {
      Mreg[e] = *(const float4*)(mp + 4 * e);
      vp[e] = make_float4(0.f, 0.f, 0.f, 0.f);
    }
  }
  __syncthreads();

  unsigned b = 0;
  for (int t = 0;; ++t) {
    // =================== P phase ===================
    if (t > 0) {
      {  // S1: partial column-sums of cnp
        const int n = tid & 127, hh = tid >> 7;
        float p = 0.f;
        const float* cp = cnp + (hh * 16) * Nn + n;
#pragma unroll
        for (int q = 0; q < 16; ++q) p += cp[q * Nn];
        s_part[hh][n] = p;
      }
      __syncthreads();
      // S2: u_{t-1} = cn_{t-1} - K x_{t-1}
      if (tid < Nn) s_u[tid] = s_part[0][tid] + s_part[1][tid] - kx[tid];
      __syncthreads();
      if (tid < Nn && ((t - 1) & 127) == g) u2[(size_t)(t - 1) * Nn + tid] = s_u[tid];
      if (tid == 0) s_urow[t - 1] = s_u[g];
      {  // g_{t-1} = 2 R u for owned n-slice
        float p = 0.f;
        const float* rr = Rm + (n0 + jj) * Nn + dsub * 16;
#pragma unroll
        for (int q = 0; q < 16; ++q) p += rr[q] * s_u[dsub * 16 + q];
        p += __shfl_xor(p, 1);
        p += __shfl_xor(p, 2);
        p += __shfl_xor(p, 4);
        if (dsub == 0) s_g[jj] = 2.f * p;
      }
      if (t < Tt && tid < 128) {  // x_t, new_w_{t-1} for owned d-pair (waves 0,1)
        const int dd = tid >> 6, l = tid & 63;
        float pS = s_S[dd][l] * s_u[l] + s_S[dd][l + 64] * s_u[l + 64];
        float pB = s_B[dd][l] * s_u[l] + s_B[dd][l + 64] * s_u[l + 64];
        float pA = 0.f;
#pragma unroll
        for (int q = 0; q < 4; ++q) pA += s_A[dd][l + 64 * q] * s_x[l + 64 * q];
#pragma unroll
        for (int off = 1; off < 64; off <<= 1) {
          pS += __shfl_xor(pS, off);
          pB += __shfl_xor(pB, off);
          pA += __shfl_xor(pA, off);
        }
        if (l == 0) {
          const float xt = s_xh[dd] + pS;          // x_t = x_hist_{t-1} + S u_{t-1}
          s_w[dd][t - 1] = xt - pA - pB;           // new_w_{t-1} = x_t - A x_{t-1} - B u_{t-1}
          xs[(size_t)t * Dd + 2 * g + dd] = xt;
        }
      }
      __syncthreads();
    }
    if (t == Tt) break;

    {  // S4 partials: P_hist_t row (n=g) and v_t rows (d = 2g, 2g+1)
      const int ssub = tid >> 5, lane = tid & 31;
      float a4 = 0.f;
      if (t > 0 && lane < HSk) {
        for (int s = ssub; s < t; s += 8)
          a4 += s_urow[s] * phis[(t - s) * HSk + lane];
      }
      s_red4[tid] = a4;
      const int dd = tid >> 7, r = tid & 127;
      const int s5 = r >> 5, h5 = r & 31;
      float a5 = 0.f;
      for (int s = s5; s < t; s += 4)
        a5 += s_w[dd][s] * phi[(t - 1 - s) * Hh + h5];
      s_red[tid] = a5;
    }
    __syncthreads();
    if (t > 0 && tid < HSk) {  // P_hist combine -> phT[k][n=g]
      float p = 0.f;
#pragma unroll
      for (int q = 0; q < 8; ++q) p += s_red4[q * 32 + tid];
      phT[tid * Nn + g] = p;
    }
    if (tid < 64) {  // v combine (+ W0 column term) -> vbuf[h][d]
      const int dd = tid >> 5, h5 = tid & 31;
      float v = s_w0[dd] * phi[t * Hh + h5];
#pragma unroll
      for (int q = 0; q < 4; ++q) v += s_red[dd * 128 + q * 32 + h5];
      vbuf[h5 * Dd + 2 * g + dd] = v;
    }

    grid_sync(flags, gen, ++b);

    // =================== Q phase ===================
    s_x[tid] = (t == 0) ? x0[tid] : xs[(size_t)t * Dd + tid];
    __syncthreads();

    {  // fused M SGD update (with v_{t-1}) + dot with v_t -> cnp
      float4 vc[8];
      const float* vrow = vbuf + h * Dd + dsub * 32;
#pragma unroll
      for (int e = 0; e < 8; ++e) vc[e] = *(const float4*)(vrow + 4 * e);
      float coef = 0.f;
      if (t > 0) coef = ETAf * sig4h * s_g[jj];
      float acc = 0.f;
#pragma unroll
      for (int e = 0; e < 8; ++e) {
        Mreg[e].x -= coef * vp[e].x;
        Mreg[e].y -= coef * vp[e].y;
        Mreg[e].z -= coef * vp[e].z;
        Mreg[e].w -= coef * vp[e].w;
        acc += Mreg[e].x * vc[e].x + Mreg[e].y * vc[e].y +
               Mreg[e].z * vc[e].z + Mreg[e].w * vc[e].w;
        vp[e] = vc[e];
      }
      acc += __shfl_xor(acc, 1);
      acc += __shfl_xor(acc, 2);
      acc += __shfl_xor(acc, 4);
      if (dsub == 0) cnp[h * Nn + n0 + jj] = sig4h * acc;
    }
    {  // x_hist_t for owned d-pair + kx_t = K[g,:] x_t
      float accx = 0.f;
      if (t > 0) {
        const int dd = tid >> 7, n = tid & 127;
        const int d = 2 * g + dd;
#pragma unroll
        for (int k = 0; k < HSk; ++k)
          accx += Ms[(k * Dd + d) * Nn + n] * phT[k * Nn + n];
      }
      float acck = s_K[tid] * s_x[tid];
#pragma unroll
      for (int off = 1; off < 64; off <<= 1) {
        accx += __shfl_xor(accx, off);
        acck += __shfl_xor(acck, off);
      }
      __syncthreads();
      if ((tid & 63) == 0) {
        s_red[tid >> 6] = accx;
        s_red[8 + (tid >> 6)] = acck;
      }
      __syncthreads();
      if (tid < 2) s_xh[tid] = s_red[2 * tid] + s_red[2 * tid + 1];
      if (tid == 0) kx[g] = s_red[8] + s_red[9] + s_red[10] + s_red[11];
    }

    grid_sync(flags, gen, ++b);
  }

  // =================== deferred losses pass ===================
  for (int tt = g; tt < Tt; tt += NWG) {
    const float* xsrc = (tt == 0) ? x0 : (xs + (size_t)tt * Dd);
    __syncthreads();
    s_x[tid] = xsrc[tid];
    __syncthreads();
    float qp = 0.f;
    for (int d2 = 0; d2 < Dd; ++d2) qp += Qmat[d2 * Dd + tid] * s_x[d2];
    float tot = qp * s_x[tid];                       // (x^T Q)[tid] * x[tid]
    if (tid < Nn) {
      const float un = u2[(size_t)tt * Nn + tid];
      float rp = 0.f;
      for (int n2 = 0; n2 < Nn; ++n2) rp += Rm[n2 * Nn + tid] * u2[(size_t)tt * Nn + n2];
      tot += un * rp;                                // u^T R u contribution
    }
#pragma unroll
    for (int off = 1; off < 64; off <<= 1) tot += __shfl_xor(tot, off);
    __syncthreads();
    if ((tid & 63) == 0) s_red[tid >> 6] = tot;
    __syncthreads();
    if (tid == 0) out[tt] = s_red[0] + s_red[1] + s_red[2] + s_red[3];
  }
}

extern "C" void kernel_launch(void* const* d_in, const int* in_sizes, int n_in,
                              void* d_out, int out_size, void* d_ws, size_t ws_size,
                              hipStream_t stream) {
  (void)in_sizes; (void)n_in; (void)out_size; (void)ws_size;
  const float* A   = (const float*)d_in[0];
  const float* B   = (const float*)d_in[1];
  const float* Qm  = (const float*)d_in[2];
  const float* R   = (const float*)d_in[3];
  const float* K   = (const float*)d_in[4];
  const float* phi = (const float*)d_in[5];
  const float* sig = (const float*)d_in[6];
  const float* phs = (const float*)d_in[7];
  const float* M0  = (const float*)d_in[8];
  const float* Ms  = (const float*)d_in[9];
  const float* x0  = (const float*)d_in[10];
  const float* W0  = (const float*)d_in[11];
  // d_in[12] = U0 (all zeros, unused)

  unsigned* bar = (unsigned*)d_ws;
  float* fws = (float*)((char*)d_ws + 12288);

  // barrier state must be re-zeroed every call (ws poisoned once, never restored)
  init_bar_kernel<<<1, 256, 0, stream>>>(bar, NWG * 16 + 16);
  osf_main<<<NWG, NT, 0, stream>>>(A, B, Qm, R, K, phi, sig, phs, M0, Ms, x0, W0,
                                   (float*)d_out, bar, fws);
}

// Round 2
// 4371.494 us; speedup vs baseline: 2.5895x; 2.5895x over previous
//
#include <hip/hip_runtime.h>

#define Dd 256
#define Nn 128
#define Hh 32
#define HSk 20
#define Tt 256
#define NWG 128
#define NT 256
#define ETAf 1e-3f

// ------------- coherent (L1/L2-bypassing) access helpers -------------
__device__ __forceinline__ unsigned ld_ag(const unsigned* p) {
  return __hip_atomic_load(p, __ATOMIC_RELAXED, __HIP_MEMORY_SCOPE_AGENT);
}
__device__ __forceinline__ void st_ag(unsigned* p, unsigned v) {
  __hip_atomic_store(p, v, __ATOMIC_RELAXED, __HIP_MEMORY_SCOPE_AGENT);
}
__device__ __forceinline__ float ldg_c(const float* p) {
  return __hip_atomic_load(p, __ATOMIC_RELAXED, __HIP_MEMORY_SCOPE_AGENT);
}
__device__ __forceinline__ void stg_c(float* p, float v) {
  __hip_atomic_store(p, v, __ATOMIC_RELAXED, __HIP_MEMORY_SCOPE_AGENT);
}

// ---------------- grid barrier: no cache flushes ----------------
// All cross-WG data uses bypassing (sc0 sc1) accesses, so visibility is at the
// coherent L3 already; the barrier only needs vmcnt(0) drain + flag handshake.
__device__ __forceinline__ void grid_sync(unsigned* flags, unsigned* gen, unsigned b) {
  asm volatile("s_waitcnt vmcnt(0)" ::: "memory");  // own bypassed stores committed
  __syncthreads();
  if (blockIdx.x == 0) {
    const int t = threadIdx.x;
    if (t > 0 && t < NWG) {
      while (ld_ag(&flags[t * 16]) < b) __builtin_amdgcn_s_sleep(1);
    }
    __syncthreads();
    if (t == 0) st_ag(gen, b);
  } else if (threadIdx.x == 0) {
    st_ag(&flags[blockIdx.x * 16], b);
    while (ld_ag(gen) < b) __builtin_amdgcn_s_sleep(1);
  }
  asm volatile("" ::: "memory");  // compiler barrier: no hoisting of data loads
  __syncthreads();
}

__global__ void init_bar_kernel(unsigned* bar, int n) {
  for (int i = threadIdx.x; i < n; i += blockDim.x) bar[i] = 0u;
}

// ---------------- main persistent kernel ----------------
__global__ __launch_bounds__(NT, 1)
void osf_main(const float* __restrict__ Am, const float* __restrict__ Bm,
              const float* __restrict__ Qmat, const float* __restrict__ Rm,
              const float* __restrict__ Km, const float* __restrict__ phi,
              const float* __restrict__ sigma, const float* __restrict__ phis,
              const float* __restrict__ M0, const float* __restrict__ Ms,
              const float* __restrict__ x0, const float* __restrict__ W0,
              float* __restrict__ out, unsigned* __restrict__ bar,
              float* __restrict__ fws) {
  const int g = blockIdx.x;
  const int tid = threadIdx.x;

  unsigned* flags = bar;
  unsigned* gen = bar + NWG * 16;

  float* cnp  = fws;                    // [32][128]  sig4[h]*<M[h,n,:],v[:,h]>
  float* vbuf = cnp + Hh * Nn;          // [32][256]  v_t stored [h][d]
  float* phT  = vbuf + Hh * Dd;         // [20][128]  P_hist transposed [k][n]
  float* kx   = phT + HSk * Nn;         // [128]      K @ x_t
  float* xs   = kx + Nn;                // [256][256] x_t history (row t valid t>=1)
  float* u2   = xs + Tt * Dd;           // [256][128] u_t history (same-WG use only)

  __shared__ float s_u[Nn], s_part[2][Nn], s_urow[Tt], s_w[2][Tt];
  __shared__ float s_x[Dd], s_S[2][Nn], s_A[2][Dd], s_B[2][Nn], s_K[Dd];
  __shared__ float s_g[32], s_xh[2], s_red[NT], s_red4[NT], s_w0[2];

  const int h = g >> 2;          // owned filter index (M slice)
  const int n0 = (g & 3) * 32;   // owned n-range base (M slice)
  const int jj = tid >> 3;       // 0..31: n within slice
  const int dsub = tid & 7;      // 0..7: 32-wide d chunk
  const float sig4h = sqrtf(sqrtf(sigma[h]));

  // ---- init: per-WG constant rows into LDS (ordinary cached loads) ----
  for (int i = tid; i < Dd; i += NT) {
    s_A[0][i] = Am[(2 * g) * Dd + i];
    s_A[1][i] = Am[(2 * g + 1) * Dd + i];
    s_K[i] = Km[g * Dd + i];
  }
  for (int i = tid; i < Nn; i += NT) {
    float a0 = 0.f, a1 = 0.f;
    for (int k = 0; k < HSk; ++k) {             // S[d,:] = sum_k phis[0,k]*M_stu[k,d,:]
      a0 += phis[k] * Ms[(k * Dd + 2 * g) * Nn + i];
      a1 += phis[k] * Ms[(k * Dd + 2 * g + 1) * Nn + i];
    }
    s_S[0][i] = a0;
    s_S[1][i] = a1;
    s_B[0][i] = Bm[(2 * g) * Nn + i];
    s_B[1][i] = Bm[(2 * g + 1) * Nn + i];
  }
  if (tid < 2) s_w0[tid] = W0[(2 * g + tid) * 512];   // W0[:,0] only nonzero col

  // M slice resident in registers: M[h][n0+jj][dsub*32 .. +32]
  float Mreg[32], vp[32];
  {
    const float* mp = M0 + ((size_t)(h * Nn + n0 + jj) * Dd + dsub * 32);
#pragma unroll
    for (int e = 0; e < 32; ++e) {
      Mreg[e] = mp[e];
      vp[e] = 0.f;
    }
  }
  __syncthreads();

  unsigned b = 0;
  for (int t = 0;; ++t) {
    // =================== P phase ===================
    if (t > 0) {
      {  // S1: partial column-sums of cnp (bypassed reads)
        const int n = tid & 127, hh = tid >> 7;
        float p = 0.f;
        const float* cp = cnp + (hh * 16) * Nn + n;
#pragma unroll
        for (int q = 0; q < 16; ++q) p += ldg_c(cp + q * Nn);
        s_part[hh][n] = p;
      }
      __syncthreads();
      // S2: u_{t-1} = cn_{t-1} - K x_{t-1}
      if (tid < Nn) s_u[tid] = s_part[0][tid] + s_part[1][tid] - ldg_c(&kx[tid]);
      __syncthreads();
      if (tid < Nn && ((t - 1) & 127) == g) u2[(size_t)(t - 1) * Nn + tid] = s_u[tid];
      if (tid == 0) s_urow[t - 1] = s_u[g];
      {  // g_{t-1} = 2 R u for owned n-slice
        float p = 0.f;
        const float* rr = Rm + (n0 + jj) * Nn + dsub * 16;
#pragma unroll
        for (int q = 0; q < 16; ++q) p += rr[q] * s_u[dsub * 16 + q];
        p += __shfl_xor(p, 1);
        p += __shfl_xor(p, 2);
        p += __shfl_xor(p, 4);
        if (dsub == 0) s_g[jj] = 2.f * p;
      }
      if (t < Tt && tid < 128) {  // x_t, new_w_{t-1} for owned d-pair (waves 0,1)
        const int dd = tid >> 6, l = tid & 63;
        float pS = s_S[dd][l] * s_u[l] + s_S[dd][l + 64] * s_u[l + 64];
        float pB = s_B[dd][l] * s_u[l] + s_B[dd][l + 64] * s_u[l + 64];
        float pA = 0.f;
#pragma unroll
        for (int q = 0; q < 4; ++q) pA += s_A[dd][l + 64 * q] * s_x[l + 64 * q];
#pragma unroll
        for (int off = 1; off < 64; off <<= 1) {
          pS += __shfl_xor(pS, off);
          pB += __shfl_xor(pB, off);
          pA += __shfl_xor(pA, off);
        }
        if (l == 0) {
          const float xt = s_xh[dd] + pS;          // x_t = x_hist_{t-1} + S u_{t-1}
          s_w[dd][t - 1] = xt - pA - pB;           // new_w_{t-1} = x_t - A x_{t-1} - B u_{t-1}
          stg_c(&xs[(size_t)t * Dd + 2 * g + dd], xt);
        }
      }
      __syncthreads();
    }
    if (t == Tt) break;

    {  // S4 partials: P_hist_t row (n=g) and v_t rows (d = 2g, 2g+1)
      const int ssub = tid >> 5, lane = tid & 31;
      float a4 = 0.f;
      if (t > 0 && lane < HSk) {
        for (int s = ssub; s < t; s += 8)
          a4 += s_urow[s] * phis[(t - s) * HSk + lane];
      }
      s_red4[tid] = a4;
      const int dd = tid >> 7, r = tid & 127;
      const int s5 = r >> 5, h5 = r & 31;
      float a5 = 0.f;
      for (int s = s5; s < t; s += 4)
        a5 += s_w[dd][s] * phi[(t - 1 - s) * Hh + h5];
      s_red[tid] = a5;
    }
    __syncthreads();
    if (t > 0 && tid < HSk) {  // P_hist combine -> phT[k][n=g]
      float p = 0.f;
#pragma unroll
      for (int q = 0; q < 8; ++q) p += s_red4[q * 32 + tid];
      stg_c(&phT[tid * Nn + g], p);
    }
    if (tid < 64) {  // v combine (+ W0 column term) -> vbuf[h][d]
      const int dd = tid >> 5, h5 = tid & 31;
      float v = s_w0[dd] * phi[t * Hh + h5];
#pragma unroll
      for (int q = 0; q < 4; ++q) v += s_red[dd * 128 + q * 32 + h5];
      stg_c(&vbuf[h5 * Dd + 2 * g + dd], v);
    }

    grid_sync(flags, gen, ++b);

    // =================== Q phase ===================
    s_x[tid] = (t == 0) ? x0[tid] : ldg_c(&xs[(size_t)t * Dd + tid]);
    __syncthreads();

    {  // fused M SGD update (with v_{t-1}) + dot with v_t -> cnp
      float vc[32];
      const float* vrow = vbuf + h * Dd + dsub * 32;
#pragma unroll
      for (int e = 0; e < 32; ++e) vc[e] = ldg_c(vrow + e);
      float coef = 0.f;
      if (t > 0) coef = ETAf * sig4h * s_g[jj];
      float acc = 0.f;
#pragma unroll
      for (int e = 0; e < 32; ++e) {
        Mreg[e] -= coef * vp[e];
        acc += Mreg[e] * vc[e];
        vp[e] = vc[e];
      }
      acc += __shfl_xor(acc, 1);
      acc += __shfl_xor(acc, 2);
      acc += __shfl_xor(acc, 4);
      if (dsub == 0) stg_c(&cnp[h * Nn + n0 + jj], sig4h * acc);
    }
    {  // x_hist_t for owned d-pair + kx_t = K[g,:] x_t
      float accx = 0.f;
      if (t > 0) {
        const int dd = tid >> 7, n = tid & 127;
        const int d = 2 * g + dd;
#pragma unroll
        for (int k = 0; k < HSk; ++k)
          accx += Ms[(k * Dd + d) * Nn + n] * ldg_c(&phT[k * Nn + n]);
      }
      float acck = s_K[tid] * s_x[tid];
#pragma unroll
      for (int off = 1; off < 64; off <<= 1) {
        accx += __shfl_xor(accx, off);
        acck += __shfl_xor(acck, off);
      }
      __syncthreads();
      if ((tid & 63) == 0) {
        s_red[tid >> 6] = accx;
        s_red[8 + (tid >> 6)] = acck;
      }
      __syncthreads();
      if (tid < 2) s_xh[tid] = s_red[2 * tid] + s_red[2 * tid + 1];
      if (tid == 0) stg_c(&kx[g], s_red[8] + s_red[9] + s_red[10] + s_red[11]);
    }

    grid_sync(flags, gen, ++b);
  }

  // =================== deferred losses pass ===================
  for (int tt = g; tt < Tt; tt += NWG) {
    __syncthreads();
    s_x[tid] = (tt == 0) ? x0[tid] : ldg_c(&xs[(size_t)tt * Dd + tid]);
    __syncthreads();
    float qp = 0.f;
    for (int d2 = 0; d2 < Dd; ++d2) qp += Qmat[d2 * Dd + tid] * s_x[d2];
    float tot = qp * s_x[tid];                       // (x^T Q)[tid] * x[tid]
    if (tid < Nn) {
      const float un = u2[(size_t)tt * Nn + tid];
      float rp = 0.f;
      for (int n2 = 0; n2 < Nn; ++n2) rp += Rm[n2 * Nn + tid] * u2[(size_t)tt * Nn + n2];
      tot += un * rp;                                // u^T R u contribution
    }
#pragma unroll
    for (int off = 1; off < 64; off <<= 1) tot += __shfl_xor(tot, off);
    __syncthreads();
    if ((tid & 63) == 0) s_red[tid >> 6] = tot;
    __syncthreads();
    if (tid == 0) out[tt] = s_red[0] + s_red[1] + s_red[2] + s_red[3];
  }
}

extern "C" void kernel_launch(void* const* d_in, const int* in_sizes, int n_in,
                              void* d_out, int out_size, void* d_ws, size_t ws_size,
                              hipStream_t stream) {
  (void)in_sizes; (void)n_in; (void)out_size; (void)ws_size;
  const float* A   = (const float*)d_in[0];
  const float* B   = (const float*)d_in[1];
  const float* Qm  = (const float*)d_in[2];
  const float* R   = (const float*)d_in[3];
  const float* K   = (const float*)d_in[4];
  const float* phi = (const float*)d_in[5];
  const float* sig = (const float*)d_in[6];
  const float* phs = (const float*)d_in[7];
  const float* M0  = (const float*)d_in[8];
  const float* Ms  = (const float*)d_in[9];
  const float* x0  = (const float*)d_in[10];
  const float* W0  = (const float*)d_in[11];
  // d_in[12] = U0 (all zeros, unused)

  unsigned* bar = (unsigned*)d_ws;
  float* fws = (float*)((char*)d_ws + 12288);

  // barrier state must be re-zeroed every call (ws poisoned once, never restored)
  init_bar_kernel<<<1, 256, 0, stream>>>(bar, NWG * 16 + 16);
  osf_main<<<NWG, NT, 0, stream>>>(A, B, Qm, R, K, phi, sig, phs, M0, Ms, x0, W0,
                                   (float*)d_out, bar, fws);
}